// Round 4
// baseline (4987.292 us; speedup 1.0000x reference)
//
#include <hip/hip_runtime.h>
#include <hip/hip_bf16.h>

// B=256, LATENT=64, HID=256, OUT=128, S=512. gates [i|f|g|o] -> 4H=1024.
//
// R4: single persistent kernel, 16 blocks x 1024 threads (16 waves).
// Block owns batch rows [16b,16b+16); wave wv owns h-cols [16wv,16wv+16) for
// all 4 gates -> w_hh register-resident (128 VGPRs/wave). Full H inside one
// block => one __syncthreads per step, no cross-CU handshake. Prologue
// (h0, x_proj fp32, w_hh->bf16 frags, out_w frags) computed in-kernel.
// Out-proj fused on waves 0-7 (16 cols each). rcp via v_rcp_f32.

typedef __bf16 v8bf __attribute__((ext_vector_type(8)));
typedef float  v4f  __attribute__((ext_vector_type(4)));

__device__ __forceinline__ float fast_rcp(float x) { return __builtin_amdgcn_rcpf(x); }
__device__ __forceinline__ float sigmoidf_(float x) {
    return fast_rcp(1.0f + __expf(-x));
}
__device__ __forceinline__ float tanhf_(float x) {
    float ax = fabsf(x);
    float e  = __expf(-2.0f * ax);
    float t  = (1.0f - e) * fast_rcp(1.0f + e);
    return copysignf(t, x);
}

constexpr int STR = 264;   // padded LDS row stride (bf16 elems)

__global__ __launch_bounds__(1024, 4) void lstm_all(
    const float* __restrict__ z,     const float* __restrict__ fc_w,
    const float* __restrict__ fc_b,  const float* __restrict__ w_ih,
    const float* __restrict__ w_hh,  const float* __restrict__ b_ih,
    const float* __restrict__ b_hh,  const float* __restrict__ out_w,
    const float* __restrict__ out_b, float* __restrict__ out)
{
    __shared__ __hip_bfloat16 hA[2][16 * STR];  // ~16.9 KB, double-buffered h tile
    __shared__ float h0f[16][256];              // 16 KB, h0 fp32 (xproj input)
    __shared__ float xps[16][1024];             // 64 KB, x_proj staging
    __shared__ float zt[16][64];                // 4 KB, z tile

    const int tid  = threadIdx.x;
    const int wv   = tid >> 6;        // 0..15
    const int lane = tid & 63;
    const int l15  = lane & 15;
    const int quad = lane >> 4;
    const int b_base = blockIdx.x * 16;
    const int jcol = wv * 16 + l15;   // owned h-col, 0..255

    // ---- w_hh fragments: fp32 -> bf16, register-resident (128 VGPRs) ----
    union U8 { __hip_bfloat16 h[8]; v8bf v; };
    v8bf wB[4][8];
    #pragma unroll
    for (int g = 0; g < 4; ++g) {
        const float* row = w_hh + (g * 256 + jcol) * 256 + quad * 8;
        #pragma unroll
        for (int ks = 0; ks < 8; ++ks) {
            U8 u;
            const float4 f0 = *(const float4*)(row + ks * 32);
            const float4 f1 = *(const float4*)(row + ks * 32 + 4);
            u.h[0] = __float2bfloat16(f0.x); u.h[1] = __float2bfloat16(f0.y);
            u.h[2] = __float2bfloat16(f0.z); u.h[3] = __float2bfloat16(f0.w);
            u.h[4] = __float2bfloat16(f1.x); u.h[5] = __float2bfloat16(f1.y);
            u.h[6] = __float2bfloat16(f1.z); u.h[7] = __float2bfloat16(f1.w);
            wB[g][ks] = u.v;
        }
    }

    // ---- out_w fragments on waves 0..7 (out cols [16wv,16wv+16)) ----
    v8bf wo[8];
    float ob = 0.f;
    const int ocol = wv * 16 + l15;
    if (wv < 8) {
        const float* row = out_w + ocol * 256 + quad * 8;
        #pragma unroll
        for (int ks = 0; ks < 8; ++ks) {
            U8 u;
            const float4 f0 = *(const float4*)(row + ks * 32);
            const float4 f1 = *(const float4*)(row + ks * 32 + 4);
            u.h[0] = __float2bfloat16(f0.x); u.h[1] = __float2bfloat16(f0.y);
            u.h[2] = __float2bfloat16(f0.z); u.h[3] = __float2bfloat16(f0.w);
            u.h[4] = __float2bfloat16(f1.x); u.h[5] = __float2bfloat16(f1.y);
            u.h[6] = __float2bfloat16(f1.z); u.h[7] = __float2bfloat16(f1.w);
            wo[ks] = u.v;
        }
        ob = out_b[ocol];
    }

    // ---- z tile ----
    zt[wv][lane] = z[(b_base + wv) * 64 + lane];
    __syncthreads();

    // ---- h0 = z @ fc_w.T + fc_b : lane does col=tid&255, rows r0..r0+3 ----
    {
        const int col = tid & 255;
        const int r0  = (tid >> 8) << 2;
        float a0 = fc_b[col], a1 = a0, a2 = a0, a3 = a0;
        for (int k = 0; k < 64; k += 4) {
            const float4 w = *(const float4*)(fc_w + col * 64 + k);
            a0 += w.x * zt[r0+0][k] + w.y * zt[r0+0][k+1] + w.z * zt[r0+0][k+2] + w.w * zt[r0+0][k+3];
            a1 += w.x * zt[r0+1][k] + w.y * zt[r0+1][k+1] + w.z * zt[r0+1][k+2] + w.w * zt[r0+1][k+3];
            a2 += w.x * zt[r0+2][k] + w.y * zt[r0+2][k+1] + w.z * zt[r0+2][k+2] + w.w * zt[r0+2][k+3];
            a3 += w.x * zt[r0+3][k] + w.y * zt[r0+3][k+1] + w.z * zt[r0+3][k+2] + w.w * zt[r0+3][k+3];
        }
        h0f[r0+0][col] = a0; h0f[r0+1][col] = a1;
        h0f[r0+2][col] = a2; h0f[r0+3][col] = a3;
        __hip_bfloat16* H = hA[0];
        H[(r0+0) * STR + col] = __float2bfloat16(a0);
        H[(r0+1) * STR + col] = __float2bfloat16(a1);
        H[(r0+2) * STR + col] = __float2bfloat16(a2);
        H[(r0+3) * STR + col] = __float2bfloat16(a3);
    }
    __syncthreads();

    // ---- x_proj = h0 @ w_ih.T + (b_ih+b_hh): lane does gate-col c=tid, 16 rows ----
    {
        const int c = tid;
        const float bias = b_ih[c] + b_hh[c];
        float acc[16];
        #pragma unroll
        for (int r = 0; r < 16; ++r) acc[r] = bias;
        for (int k = 0; k < 256; k += 4) {
            const float4 w = *(const float4*)(w_ih + c * 256 + k);
            #pragma unroll
            for (int r = 0; r < 16; ++r) {
                const float4 h = *(const float4*)(&h0f[r][k]);
                acc[r] += w.x * h.x + w.y * h.y + w.z * h.z + w.w * h.w;
            }
        }
        #pragma unroll
        for (int r = 0; r < 16; ++r) xps[r][c] = acc[r];
    }
    __syncthreads();

    // ---- gather x_proj C-init fragments ----
    v4f xpr[4];
    #pragma unroll
    for (int g = 0; g < 4; ++g)
        #pragma unroll
        for (int r = 0; r < 4; ++r)
            xpr[g][r] = xps[quad * 4 + r][g * 256 + jcol];

    float cst[4] = {0.f, 0.f, 0.f, 0.f};
    float* const obase = out + (b_base + quad * 4) * 65536 + ((wv < 8) ? ocol : 0);

    __syncthreads();

    // ---- 512 recurrent steps, one barrier each ----
    for (int t = 0; t < 512; ++t) {
        const __hip_bfloat16* A = hA[t & 1];    // h_t
        v4f acc[4];
        #pragma unroll
        for (int g = 0; g < 4; ++g) acc[g] = xpr[g];
        v4f oacc = { ob, ob, ob, ob };

        #pragma unroll
        for (int ks = 0; ks < 8; ++ks) {
            const v8bf a = *(const v8bf*)(A + l15 * STR + ks * 32 + quad * 8);
            if (wv < 8)
                oacc = __builtin_amdgcn_mfma_f32_16x16x32_bf16(a, wo[ks], oacc, 0, 0, 0);
            #pragma unroll
            for (int g = 0; g < 4; ++g)
                acc[g] = __builtin_amdgcn_mfma_f32_16x16x32_bf16(a, wB[g][ks], acc[g], 0, 0, 0);
        }

        // reference's s-th output is h_{s+1}: proj(h_t) lands at time t-1
        if (t > 0 && wv < 8) {
            #pragma unroll
            for (int r = 0; r < 4; ++r)
                obase[r * 65536 + (t - 1) * 128] = oacc[r];
        }

        // gate math -> h_{t+1} into the other LDS buffer
        __hip_bfloat16* An = hA[(t + 1) & 1];
        #pragma unroll
        for (int r = 0; r < 4; ++r) {
            const float iv = sigmoidf_(acc[0][r]);
            const float fv = sigmoidf_(acc[1][r]);
            const float gv = tanhf_  (acc[2][r]);
            const float ov = sigmoidf_(acc[3][r]);
            const float c  = fv * cst[r] + iv * gv;
            cst[r] = c;
            An[(quad * 4 + r) * STR + jcol] = __float2bfloat16(ov * tanhf_(c));
        }
        __syncthreads();
    }

    // ---- epilogue: out[:,511,:] = proj(h_512); h_512 is in hA[0] ----
    if (wv < 8) {
        const __hip_bfloat16* A = hA[0];
        v4f oacc = { ob, ob, ob, ob };
        #pragma unroll
        for (int ks = 0; ks < 8; ++ks) {
            const v8bf a = *(const v8bf*)(A + l15 * STR + ks * 32 + quad * 8);
            oacc = __builtin_amdgcn_mfma_f32_16x16x32_bf16(a, wo[ks], oacc, 0, 0, 0);
        }
        #pragma unroll
        for (int r = 0; r < 4; ++r)
            obase[r * 65536 + 511 * 128] = oacc[r];
    }
}

extern "C" void kernel_launch(void* const* d_in, const int* in_sizes, int n_in,
                              void* d_out, int out_size, void* d_ws, size_t ws_size,
                              hipStream_t stream) {
    (void)in_sizes; (void)n_in; (void)out_size; (void)d_ws; (void)ws_size;
    const float* z     = (const float*)d_in[0];
    const float* fc_w  = (const float*)d_in[1];
    const float* fc_b  = (const float*)d_in[2];
    const float* w_ih  = (const float*)d_in[3];
    const float* w_hh  = (const float*)d_in[4];
    const float* b_ih  = (const float*)d_in[5];
    const float* b_hh  = (const float*)d_in[6];
    const float* out_w = (const float*)d_in[7];
    const float* out_b = (const float*)d_in[8];
    float* out = (float*)d_out;

    hipLaunchKernelGGL(lstm_all, dim3(16), dim3(1024), 0, stream,
                       z, fc_w, fc_b, w_ih, w_hh, b_ih, b_hh, out_w, out_b, out);
}

// Round 5
// 1900.554 us; speedup vs baseline: 2.6241x; 2.6241x over previous
//
#include <hip/hip_runtime.h>
#include <hip/hip_bf16.h>

// B=256, LATENT=64, HID=256, OUT=128, S=512. gates [i|f|g|o] -> 4H=1024.
//
// R5: no cross-CU sync. 16 blocks x 512 thr (8 waves, 2/SIMD, 256-VGPR budget).
// Block owns batch rows [16b,16b+16); wave wv owns h-cols [32wv,32wv+32)
// (2 j-tiles) x 4 gates = 64 weight frags/wave (frag = 16j x 32k = 1KB bf16).
// Placement: 36 frags in VGPRs, 17 in LDS, 11 streamed from L2 per step from a
// frag-contiguous swizzled copy (wbf2, built by cvt_kernel) -> no amplification.
// h_t goes to LDS (next A-tile) + bf16 rows of d_out (hs scratch); out-proj is
// a separate in-place MFMA GEMM over d_out afterwards. Prologue (h0, fp32
// xproj) computed in-kernel.

typedef __bf16 v8bf __attribute__((ext_vector_type(8)));
typedef float  v4f  __attribute__((ext_vector_type(4)));

__device__ __forceinline__ float sigmoidf_(float x) {
    return __builtin_amdgcn_rcpf(1.0f + __expf(-x));
}
__device__ __forceinline__ float tanhf_(float x) {
    float ax = fabsf(x);
    float e  = __expf(-2.0f * ax);
    float t  = (1.0f - e) * __builtin_amdgcn_rcpf(1.0f + e);
    return copysignf(t, x);
}

// ---- wbf2 layout: frag FR(wv,jt,g,ks) = ((wv*2+jt)*4+g)*8+ks, 1024 B each;
// lane l holds 16 B at FR*1024 + l*16 = w_hh[g*256+wv*32+jt*16+(l&15)][ks*32+(l>>4)*8 + 0..7]
__global__ void cvt_kernel(const float* __restrict__ w, uint4* __restrict__ o) {
    const int gg = blockIdx.x * 256 + threadIdx.x;    // 0..32767
    const int F = gg >> 6, l = gg & 63;
    const int wv = F >> 6, rem = F & 63;
    const int jt = rem >> 5, g4 = (rem >> 3) & 3, ks = rem & 7;
    const int row = g4 * 256 + wv * 32 + jt * 16 + (l & 15);
    const int col = ks * 32 + (l >> 4) * 8;
    const float4 a = *(const float4*)(w + row * 256 + col);
    const float4 b = *(const float4*)(w + row * 256 + col + 4);
    union { __hip_bfloat16 h[8]; uint4 u; } p;
    p.h[0] = __float2bfloat16(a.x); p.h[1] = __float2bfloat16(a.y);
    p.h[2] = __float2bfloat16(a.z); p.h[3] = __float2bfloat16(a.w);
    p.h[4] = __float2bfloat16(b.x); p.h[5] = __float2bfloat16(b.y);
    p.h[6] = __float2bfloat16(b.z); p.h[7] = __float2bfloat16(b.w);
    o[gg] = p.u;
}

constexpr int STR = 264;                 // hA row stride (bf16 elems), pad kills conflicts

// jt==1 weight source tables: kind 0=reg,1=lds,2=stream
__device__ constexpr int K1[4][8] = {
    {0,0,0,0, 1, 2,2,2},
    {1,1,1,1, 1, 1,1,1},
    {1,1,1,1, 1, 2,2,2},
    {1,1,1, 2,2, 2,2,2},
};
__device__ constexpr int X1[4][8] = {
    {32,33,34,35, 0,  0,1,2},
    { 1, 2, 3, 4, 5,  6,7,8},
    { 9,10,11,12,13,  3,4,5},
    {14,15,16, 6, 7,  8,9,10},
};
// LDS staging list: lidx -> (g,ks) for jt1
__device__ constexpr int SG[17] = {0, 1,1,1,1,1,1,1,1, 2,2,2,2,2, 3,3,3};
__device__ constexpr int SK[17] = {4, 0,1,2,3,4,5,6,7, 0,1,2,3,4, 0,1,2};

__global__ __launch_bounds__(512, 2) void lstm_main(
    const float* __restrict__ z,     const float* __restrict__ fc_w,
    const float* __restrict__ fc_b,  const float* __restrict__ w_ih,
    const float* __restrict__ b_ih,  const float* __restrict__ b_hh,
    const __hip_bfloat16* __restrict__ wbf2,
    __hip_bfloat16* __restrict__ hsb)           // = d_out viewed as bf16 [B*512][256]
{
    __shared__ __align__(16) unsigned char SM[16896 + 139264];
    __hip_bfloat16* hA = (__hip_bfloat16*)SM;             // [2][16*STR]
    unsigned char*  WL = SM + 16896;                      // weight LDS / prologue alias

    const int tid  = threadIdx.x;
    const int wv   = tid >> 6;       // 0..7
    const int lane = tid & 63;
    const int l15  = lane & 15;
    const int quad = lane >> 4;
    const int b_base = blockIdx.x * 16;

    // ================= prologue (aliased LDS) =================
    float* h0f = (float*)WL;               // [16][256]  16 KB
    float* xps = (float*)(WL + 16384);     // [16][1024] 64 KB
    float* zt  = (float*)(WL + 81920);     // [16][64]    4 KB

    {   // z tile
        const float2 zv = *(const float2*)(z + b_base * 64 + tid * 2);
        *(float2*)(zt + tid * 2) = zv;
    }
    __syncthreads();

    {   // h0 = z @ fc_w.T + fc_b  (fp32 exact). thread: col=tid&255, 8 rows
        const int col = tid & 255;
        const int r0  = (tid >> 8) * 8;
        float a[8];
        const float bias = fc_b[col];
        #pragma unroll
        for (int r = 0; r < 8; ++r) a[r] = bias;
        for (int k = 0; k < 64; k += 4) {
            const float4 w = *(const float4*)(fc_w + col * 64 + k);
            #pragma unroll
            for (int r = 0; r < 8; ++r) {
                const float4 h = *(const float4*)(zt + (r0 + r) * 64 + k);
                a[r] += w.x * h.x + w.y * h.y + w.z * h.z + w.w * h.w;
            }
        }
        #pragma unroll
        for (int r = 0; r < 8; ++r) {
            h0f[(r0 + r) * 256 + col] = a[r];
            hA[(r0 + r) * STR + col] = __float2bfloat16(a[r]);
        }
    }
    __syncthreads();

    {   // x_proj = h0 @ w_ih.T + (b_ih + b_hh)  (fp32 exact). thread: cols tid, tid+512
        const int c0 = tid, c1 = tid + 512;
        float a0[16], a1[16];
        const float bb0 = b_ih[c0] + b_hh[c0];
        const float bb1 = b_ih[c1] + b_hh[c1];
        #pragma unroll
        for (int r = 0; r < 16; ++r) { a0[r] = bb0; a1[r] = bb1; }
        for (int k = 0; k < 256; k += 4) {
            const float4 w0 = *(const float4*)(w_ih + c0 * 256 + k);
            const float4 w1 = *(const float4*)(w_ih + c1 * 256 + k);
            #pragma unroll
            for (int r = 0; r < 16; ++r) {
                const float4 h = *(const float4*)(h0f + r * 256 + k);
                a0[r] += w0.x * h.x + w0.y * h.y + w0.z * h.z + w0.w * h.w;
                a1[r] += w1.x * h.x + w1.y * h.y + w1.z * h.z + w1.w * h.w;
            }
        }
        #pragma unroll
        for (int r = 0; r < 16; ++r) {
            xps[r * 1024 + c0] = a0[r];
            xps[r * 1024 + c1] = a1[r];
        }
    }
    __syncthreads();

    // gather xpr fragments (C-layout) before xps is overwritten
    v4f xpr[2][4];
    #pragma unroll
    for (int jt = 0; jt < 2; ++jt)
        #pragma unroll
        for (int g = 0; g < 4; ++g)
            #pragma unroll
            for (int r = 0; r < 4; ++r)
                xpr[jt][g][r] = xps[(quad * 4 + r) * 1024 + g * 256 + wv * 32 + jt * 16 + l15];
    __syncthreads();

    // ====== weights: 36 reg frags + 17 LDS frags (stream 11 stay in L2) ======
    v8bf wreg[36];
    {
        const uint4* src = (const uint4*)wbf2;
        #pragma unroll
        for (int g = 0; g < 4; ++g)
            #pragma unroll
            for (int ks = 0; ks < 8; ++ks) {      // jt0 -> reg 0..31
                const int FR = wv * 64 + g * 8 + ks;
                union { uint4 u; v8bf v; } t; t.u = src[FR * 64 + lane];
                wreg[g * 8 + ks] = t.v;
            }
        #pragma unroll
        for (int ks = 0; ks < 4; ++ks) {          // (jt1,g0,ks0..3) -> reg 32..35
            const int FR = wv * 64 + 32 + ks;
            union { uint4 u; v8bf v; } t; t.u = src[FR * 64 + lane];
            wreg[32 + ks] = t.v;
        }
        uint4* wl = (uint4*)WL;
        #pragma unroll
        for (int i = 0; i < 17; ++i) {            // LDS frags
            const int FR = wv * 64 + 32 + SG[i] * 8 + SK[i];
            wl[(wv * 17 + i) * 64 + lane] = src[FR * 64 + lane];
        }
    }

    float cst[2][4] = {{0,0,0,0},{0,0,0,0}};
    const __hip_bfloat16* sbase = wbf2 + (size_t)(wv * 64 + 32) * 512 + lane * 8;
    const __hip_bfloat16* wlbase = (const __hip_bfloat16*)WL + (size_t)(wv * 17) * 512 + lane * 8;
    // hs base: ((b_base+quad*4+r)*512 + t)*256 + wv*32 + jt*16 + l15
    __hip_bfloat16* hs0 = hsb + (size_t)(b_base + quad * 4) * 131072 + wv * 32 + l15;

    __syncthreads();

    // ================= 512 recurrent steps =================
    for (int t = 0; t < 512; ++t) {
        const __hip_bfloat16* A = hA + (t & 1) * (16 * STR);
        v4f acc[2][4];

        #pragma unroll
        for (int ks = 0; ks < 8; ++ks) {
            const v8bf a = *(const v8bf*)(A + l15 * STR + ks * 32 + quad * 8);
            #pragma unroll
            for (int g = 0; g < 4; ++g) {
                // jt = 0 (always register-resident)
                acc[0][g] = __builtin_amdgcn_mfma_f32_16x16x32_bf16(
                    a, wreg[g * 8 + ks], (ks == 0) ? xpr[0][g] : acc[0][g], 0, 0, 0);
                // jt = 1 (reg / LDS / L2-stream per table)
                v8bf w;
                if (K1[g][ks] == 0)      w = wreg[X1[g][ks]];
                else if (K1[g][ks] == 1) w = *(const v8bf*)(wlbase + X1[g][ks] * 512);
                else                     w = *(const v8bf*)(sbase + (g * 8 + ks) * 512);
                acc[1][g] = __builtin_amdgcn_mfma_f32_16x16x32_bf16(
                    a, w, (ks == 0) ? xpr[1][g] : acc[1][g], 0, 0, 0);
            }
        }

        // gate math; h_{t+1} -> other LDS buffer + hs (bf16 rows of d_out)
        __hip_bfloat16* An = hA + ((t + 1) & 1) * (16 * STR);
        #pragma unroll
        for (int jt = 0; jt < 2; ++jt)
            #pragma unroll
            for (int r = 0; r < 4; ++r) {
                const float iv = sigmoidf_(acc[jt][0][r]);
                const float fv = sigmoidf_(acc[jt][1][r]);
                const float gv = tanhf_  (acc[jt][2][r]);
                const float ov = sigmoidf_(acc[jt][3][r]);
                const float c  = fv * cst[jt][r] + iv * gv;
                cst[jt][r] = c;
                const __hip_bfloat16 hb = __float2bfloat16(ov * tanhf_(c));
                An[(quad * 4 + r) * STR + wv * 32 + jt * 16 + l15] = hb;
                hs0[(size_t)r * 131072 + (size_t)t * 256 + jt * 16] = hb;
            }
        __syncthreads();
    }
}

// ---- out-projection, in place over d_out: reads bf16 hs rows, writes fp32 out ----
__global__ __launch_bounds__(512, 2) void outproj_kernel(
    void* __restrict__ io, const float* __restrict__ out_w, const float* __restrict__ out_b)
{
    __shared__ __hip_bfloat16 tile[256 * STR];            // 256 rows x 264, 135168 B
    const __hip_bfloat16* hsb = (const __hip_bfloat16*)io;
    float* outp = (float*)io;

    const int tid  = threadIdx.x;
    const int wv   = tid >> 6;       // 0..7
    const int lane = tid & 63;
    const int l15  = lane & 15;
    const int quad = lane >> 4;
    const int m0   = blockIdx.x * 256;                    // (b,t) row base

    // stage 256x256 bf16 rows -> LDS (before any write: in-place safe)
    {
        const uint4* src = (const uint4*)(hsb + (size_t)m0 * 256);
        #pragma unroll
        for (int i = 0; i < 16; ++i) {
            const int cid = tid + i * 512;                // 0..8191 chunks of 16 B
            const int row = cid >> 5, c8 = (cid & 31) * 8;
            *(uint4*)&tile[row * STR + c8] = src[cid];
        }
    }
    __syncthreads();

    const int mbase = wv * 32;
    for (int nt = 0; nt < 8; ++nt) {
        union U8 { __hip_bfloat16 h[8]; v8bf v; };
        v8bf wo[8];
        #pragma unroll
        for (int ks = 0; ks < 8; ++ks) {
            const float* wr = out_w + (nt * 16 + l15) * 256 + ks * 32 + quad * 8;
            const float4 f0 = *(const float4*)wr;
            const float4 f1 = *(const float4*)(wr + 4);
            U8 u;
            u.h[0] = __float2bfloat16(f0.x); u.h[1] = __float2bfloat16(f0.y);
            u.h[2] = __float2bfloat16(f0.z); u.h[3] = __float2bfloat16(f0.w);
            u.h[4] = __float2bfloat16(f1.x); u.h[5] = __float2bfloat16(f1.y);
            u.h[6] = __float2bfloat16(f1.z); u.h[7] = __float2bfloat16(f1.w);
            wo[ks] = u.v;
        }
        const float ob = out_b[nt * 16 + l15];
        #pragma unroll
        for (int mt = 0; mt < 2; ++mt) {
            v4f oacc = { ob, ob, ob, ob };
            #pragma unroll
            for (int ks = 0; ks < 8; ++ks) {
                const v8bf a = *(const v8bf*)&tile[(mbase + mt * 16 + l15) * STR + ks * 32 + quad * 8];
                oacc = __builtin_amdgcn_mfma_f32_16x16x32_bf16(a, wo[ks], oacc, 0, 0, 0);
            }
            #pragma unroll
            for (int r = 0; r < 4; ++r)
                outp[(size_t)(m0 + mbase + mt * 16 + quad * 4 + r) * 128 + nt * 16 + l15] = oacc[r];
        }
    }
}

extern "C" void kernel_launch(void* const* d_in, const int* in_sizes, int n_in,
                              void* d_out, int out_size, void* d_ws, size_t ws_size,
                              hipStream_t stream) {
    (void)in_sizes; (void)n_in; (void)out_size; (void)ws_size;
    const float* z     = (const float*)d_in[0];
    const float* fc_w  = (const float*)d_in[1];
    const float* fc_b  = (const float*)d_in[2];
    const float* w_ih  = (const float*)d_in[3];
    const float* w_hh  = (const float*)d_in[4];
    const float* b_ih  = (const float*)d_in[5];
    const float* b_hh  = (const float*)d_in[6];
    const float* out_w = (const float*)d_in[7];
    const float* out_b = (const float*)d_in[8];

    __hip_bfloat16* wbf2 = (__hip_bfloat16*)d_ws;         // 512 KB swizzled w_hh

    hipLaunchKernelGGL(cvt_kernel, dim3(128), dim3(256), 0, stream, w_hh, (uint4*)wbf2);
    hipLaunchKernelGGL(lstm_main,  dim3(16),  dim3(512), 0, stream,
                       z, fc_w, fc_b, w_ih, b_ih, b_hh, wbf2, (__hip_bfloat16*)d_out);
    hipLaunchKernelGGL(outproj_kernel, dim3(512), dim3(512), 0, stream,
                       d_out, out_w, out_b);
}